// Round 9
// baseline (285.392 us; speedup 1.0000x reference)
//
#include <hip/hip_runtime.h>
#include <hip/hip_bf16.h>
#include <cstdint>
#include <cstddef>

#define B_ 4
#define S_ 2048
#define E_ 768
#define H_ 12
#define D_ 64

typedef __bf16 bf16x8 __attribute__((ext_vector_type(8)));
typedef float f32x4 __attribute__((ext_vector_type(4)));

__constant__ float c_slopes[12] = {
    0.6299605249f, 0.396850263f, 0.25f, 0.1574901312f,
    0.0992125657f, 0.0625f, 0.0393725328f, 0.0248031414f,
    0.015625f, 0.0098431332f, 0.0062007854f, 0.00390625f};

__device__ __forceinline__ unsigned short f2bf_u(float f) {
    unsigned u = __builtin_bit_cast(unsigned, f);
    u += 0x7fffu + ((u >> 16) & 1u);   // round-to-nearest-even
    return (unsigned short)(u >> 16);
}
__device__ __forceinline__ __bf16 f2bf(float f) {
    unsigned short s = f2bf_u(f);
    return __builtin_bit_cast(__bf16, s);
}

// async global->LDS, 16B per lane, dest = wave-uniform base + lane*16
__device__ __forceinline__ void gload_lds16(const void* g, void* l) {
    __builtin_amdgcn_global_load_lds(
        (const __attribute__((address_space(1))) unsigned int*)g,
        (__attribute__((address_space(3))) unsigned int*)l, 16, 0, 0);
}

// ---------------------------------------------------------------------------
// prep: x fp32 -> bf16 (6.29M elems)
// ---------------------------------------------------------------------------
__global__ __launch_bounds__(256) void cvt_x(const float* __restrict__ src,
                                             __bf16* __restrict__ dst) {
    int i = (blockIdx.x * 256 + threadIdx.x) * 4;
    float4 v = *(const float4*)(src + i);
    ushort4 o;
    o.x = f2bf_u(v.x); o.y = f2bf_u(v.y); o.z = f2bf_u(v.z); o.w = f2bf_u(v.w);
    *(ushort4*)((unsigned short*)dst + i) = o;
}

// ---------------------------------------------------------------------------
// prep: W fp32 [k][n] -> Wt bf16 [n][k]; z picks which of 4 matrices
// ---------------------------------------------------------------------------
__global__ __launch_bounds__(256) void wtrans(const float* __restrict__ W0,
                                              const float* __restrict__ W1,
                                              const float* __restrict__ W2,
                                              const float* __restrict__ W3,
                                              __bf16* __restrict__ Wt) {
    const float* W = blockIdx.z == 0 ? W0 : blockIdx.z == 1 ? W1
                   : blockIdx.z == 2 ? W2 : W3;
    __bf16* out = Wt + (size_t)blockIdx.z * E_ * E_;
    __shared__ alignas(16) __bf16 ts[64 * 72];
    const int t = threadIdx.x;
    const int k0 = blockIdx.y * 64, n0 = blockIdx.x * 64;
#pragma unroll
    for (int i = 0; i < 4; i++) {
        int idx = i * 256 + t;          // 1024 float4 chunks
        int row = idx >> 4, c4 = idx & 15;
        float4 v = *(const float4*)(W + (size_t)(k0 + row) * E_ + n0 + c4 * 4);
        ts[(c4 * 4 + 0) * 72 + row] = f2bf(v.x);
        ts[(c4 * 4 + 1) * 72 + row] = f2bf(v.y);
        ts[(c4 * 4 + 2) * 72 + row] = f2bf(v.z);
        ts[(c4 * 4 + 3) * 72 + row] = f2bf(v.w);
    }
    __syncthreads();
#pragma unroll
    for (int i = 0; i < 2; i++) {
        int idx = i * 256 + t;          // 512 chunks of 8 bf16
        int r = idx >> 3, c8 = idx & 7;
        *(uint4*)((unsigned short*)out + (size_t)(n0 + r) * E_ + k0 + c8 * 8) =
            *(const uint4*)((const unsigned short*)ts + r * 72 + c8 * 8);
    }
}

// ---------------------------------------------------------------------------
// GEMM: out = A(8192x768 bf16) @ Wt^T + bias. Wt is [n][k] bf16.
// R7 single-BK32 m97-style staging (best measured; R8 BK=64 was neutral).
// PERM: z=0,1 -> Q,K natural [B,H,S,D]; z=2 -> V written TRANSPOSED as
// [bh][d][s] (4 acc rows are consecutive s -> packed 8B stores), killing
// the separate vtrans kernel.
// ---------------------------------------------------------------------------
template <bool PERM>
__global__ __launch_bounds__(256) void gemm_bf(
    const __bf16* __restrict__ A, const __bf16* __restrict__ WtAll,
    const float* __restrict__ b0, const float* __restrict__ b1,
    const float* __restrict__ b2,
    float* __restrict__ outF, __bf16* __restrict__ outB_base) {
    constexpr int Kd = E_, N = E_;
    __shared__ alignas(16) __bf16 Asm[128 * 32];   // 64B rows, no pad (m97)
    __shared__ alignas(16) __bf16 Bsm[128 * 32];

    const int t = threadIdx.x;
    const int w = t >> 6, lane = t & 63;
    const int qm = lane & 15, quad = lane >> 4;
    const int m0 = blockIdx.y * 128, n0 = blockIdx.x * 128;
    const int wm = (w >> 1) * 64, wn = (w & 1) * 64;
    const int z = blockIdx.z;
    const __bf16* Wt = WtAll + (size_t)z * Kd * N;
    const float* bias = PERM ? (z == 0 ? b0 : z == 1 ? b1 : b2) : b0;
    __bf16* outB = PERM ? outB_base + (size_t)z * ((size_t)B_ * S_ * E_) : nullptr;

    // staging: 1024B wave-chunk = 16 rows x 64B; wave w owns chunks {2w,2w+1}
    const int crow = lane >> 2;       // row within chunk
    const int ccol = lane & 3;        // 16B quarter within row

    f32x4 acc[4][4] = {};

    for (int k0 = 0; k0 < Kd; k0 += 32) {
#pragma unroll
        for (int cc = 0; cc < 2; cc++) {
            int chunk = w * 2 + cc;
            int row = chunk * 16 + crow;
            gload_lds16((const unsigned short*)A + (size_t)(m0 + row) * Kd + k0 + ccol * 8,
                        Asm + chunk * 512);
            gload_lds16((const unsigned short*)Wt + (size_t)(n0 + row) * Kd + k0 + ccol * 8,
                        Bsm + chunk * 512);
        }
        __syncthreads();

        bf16x8 af[4], bg[4];
#pragma unroll
        for (int i = 0; i < 4; i++)
            af[i] = *(const bf16x8*)(Asm + (wm + i * 16 + qm) * 32 + quad * 8);
#pragma unroll
        for (int j = 0; j < 4; j++)
            bg[j] = *(const bf16x8*)(Bsm + (wn + j * 16 + qm) * 32 + quad * 8);
#pragma unroll
        for (int i = 0; i < 4; i++)
#pragma unroll
            for (int j = 0; j < 4; j++)
                acc[i][j] = __builtin_amdgcn_mfma_f32_16x16x32_bf16(
                    af[i], bg[j], acc[i][j], 0, 0, 0);
        __syncthreads();
    }

    // epilogue: C/D layout col=lane&15, row=quad*4+reg
#pragma unroll
    for (int i = 0; i < 4; i++) {
#pragma unroll
        for (int j = 0; j < 4; j++) {
            int col = n0 + wn + j * 16 + qm;
            float bvv = bias[col];
            int rowb = m0 + wm + i * 16 + quad * 4;
            if (PERM && z == 2) {
                // V -> Vt [bh][d][s]: rows r are consecutive s, pack 4 bf16
                int b = rowb >> 11, s = rowb & (S_ - 1);
                int h = col >> 6, d = col & (D_ - 1);
                unsigned short pk4[4];
#pragma unroll
                for (int r = 0; r < 4; r++) pk4[r] = f2bf_u(acc[i][j][r] + bvv);
                uint2 pv;
                pv.x = (unsigned)pk4[0] | ((unsigned)pk4[1] << 16);
                pv.y = (unsigned)pk4[2] | ((unsigned)pk4[3] << 16);
                *(uint2*)((unsigned short*)outB +
                          ((size_t)(b * H_ + h) * D_ + d) * S_ + s) = pv;
            } else {
#pragma unroll
                for (int r = 0; r < 4; r++) {
                    int row = rowb + r;
                    float val = acc[i][j][r] + bvv;
                    if (PERM) {
                        int b = row >> 11, s = row & (S_ - 1);
                        int h = col >> 6, d = col & (D_ - 1);
                        outB[(((size_t)(b * H_ + h)) * S_ + s) * D_ + d] = f2bf(val);
                    } else {
                        outF[(size_t)row * N + col] = val;
                    }
                }
            }
        }
    }
}

// ---------------------------------------------------------------------------
// Flash attention (S^T formulation, analytic-max softmax, causal + ALiBi).
// R9: double-buffered K/V staging with ONE barrier per iteration. Tile kt+1
// is staged into buf[cur^1] while computing tile kt from buf[cur]; the
// end-of-iter barrier both publishes the next buffer and protects the one
// being overwritten (a wave writing buf[(kt+1)&1] has passed the end-of-
// (kt-1) barrier, so no wave can still be reading that buffer). LDS 45 KB
// -> 3 blocks/CU; the staging drain leaves the critical path.
// ---------------------------------------------------------------------------
__global__ __launch_bounds__(256, 3) void attn_k(
    const __bf16* __restrict__ Q, const __bf16* __restrict__ K,
    const __bf16* __restrict__ Vt, __bf16* __restrict__ O) {
    __shared__ alignas(16) __bf16 Ksm[2][64 * 72];   // [key][d]
    __shared__ alignas(16) __bf16 Vsm[2][64 * 72];   // [d][key]
    __shared__ alignas(16) __bf16 Psm[4 * 16 * 72];  // per-wave P [q][key]

    const int t = threadIdx.x;
    const int w = t >> 6, lane = t & 63;
    const int qm = lane & 15, quad = lane >> 4;
    const int qt = 31 - (int)blockIdx.x;          // longest first
    const int bh = blockIdx.y;
    const float c2 = c_slopes[bh % H_] * 1.44269504f;     // slope * log2(e)
    const size_t base = (size_t)bh * S_ * D_;

    // Q B-fragments (lane qm = q-col, contiguous over d)
    const int bb = qt * 64 + w * 16;
    const __bf16* qp = Q + base + (size_t)(bb + qm) * D_ + quad * 8;
    bf16x8 qf0 = *(const bf16x8*)qp;
    bf16x8 qf1 = *(const bf16x8*)(qp + 32);

    f32x4 oacc[4] = {};
    float lsum = 0.f;
    __bf16* Pw = Psm + w * 16 * 72;

    // staging addressing: 64 rows x 64 cols = 512 chunks of 8 bf16
    const int srow = t >> 3, sc = t & 7;
    const unsigned short* Kg = (const unsigned short*)K + base;
    const unsigned short* Vg = (const unsigned short*)Vt + base;

    // pre-stage tile 0 into buffer 0
#pragma unroll
    for (int i = 0; i < 2; i++) {
        *(uint4*)((unsigned short*)Ksm[0] + (srow + i * 32) * 72 + sc * 8) =
            *(const uint4*)(Kg + (size_t)(srow + i * 32) * D_ + sc * 8);
        *(uint4*)((unsigned short*)Vsm[0] + (srow + i * 32) * 72 + sc * 8) =
            *(const uint4*)(Vg + (size_t)(srow + i * 32) * S_ + sc * 8);
    }
    __syncthreads();

    for (int kt = 0; kt <= qt; kt++) {
        const int cur = kt & 1;
        const __bf16* Kc = Ksm[cur];
        const __bf16* Vc = Vsm[cur];

        // stage tile kt+1 into the other buffer (overlaps compute below)
        if (kt < qt) {
            const int nb = cur ^ 1;
            const int kn = (kt + 1) * 64;
#pragma unroll
            for (int i = 0; i < 2; i++) {
                *(uint4*)((unsigned short*)Ksm[nb] + (srow + i * 32) * 72 + sc * 8) =
                    *(const uint4*)(Kg + (size_t)(kn + srow + i * 32) * D_ + sc * 8);
                *(uint4*)((unsigned short*)Vsm[nb] + (srow + i * 32) * 72 + sc * 8) =
                    *(const uint4*)(Vg + (size_t)(srow + i * 32) * S_ + kn + sc * 8);
            }
        }

        // K A-frags (m=key) and V B-frags (n=d)
        bf16x8 ak[4][2], bv[4][2];
#pragma unroll
        for (int i = 0; i < 4; i++) {
            ak[i][0] = *(const bf16x8*)(Kc + (16 * i + qm) * 72 + quad * 8);
            ak[i][1] = *(const bf16x8*)(Kc + (16 * i + qm) * 72 + 32 + quad * 8);
        }
#pragma unroll
        for (int jd = 0; jd < 4; jd++) {
            bv[jd][0] = *(const bf16x8*)(Vc + (16 * jd + qm) * 72 + quad * 8);
            bv[jd][1] = *(const bf16x8*)(Vc + (16 * jd + qm) * 72 + 32 + quad * 8);
        }

        // S^T = K Q^T : lane (qm,quad) reg r holds S^T[key=16i+4quad+r][q=qm]
        f32x4 st[4];
#pragma unroll
        for (int i = 0; i < 4; i++) {
            f32x4 zz = {0.f, 0.f, 0.f, 0.f};
            zz = __builtin_amdgcn_mfma_f32_16x16x32_bf16(ak[i][0], qf0, zz, 0, 0, 0);
            zz = __builtin_amdgcn_mfma_f32_16x16x32_bf16(ak[i][1], qf1, zz, 0, 0, 0);
            st[i] = zz;
        }

        // analytic-max softmax: ALiBi max over keys is at k=0 (slope*(q-k)),
        // so subtracting slope*q gives exponent qk*scale*log2e - c2*key:
        // q-independent, bounded above by ~+4, no shuffles/running max.
        const int qi = bb + qm;
        const bool nomask = (kt * 64 + 63) <= bb;
        float ls = 0.f;
        unsigned pk[4][2];
#pragma unroll
        for (int i = 0; i < 4; i++) {
            float bi = -c2 * (float)(kt * 64 + 16 * i + 4 * quad);
            float p[4];
#pragma unroll
            for (int r = 0; r < 4; r++) {
                float tt = st[i][r] * 0.18033688f + (bi - c2 * (float)r);
                float pp = __builtin_amdgcn_exp2f(tt);
                if (!nomask) {
                    int key = kt * 64 + 16 * i + 4 * quad + r;
                    pp = (key > qi) ? 0.f : pp;
                }
                ls += pp;
                p[r] = pp;
            }
            // pack 4 fp32 -> 4 bf16 (round-half-up + v_perm byte select)
            unsigned u0 = __builtin_bit_cast(unsigned, p[0]) + 0x8000u;
            unsigned u1 = __builtin_bit_cast(unsigned, p[1]) + 0x8000u;
            unsigned u2 = __builtin_bit_cast(unsigned, p[2]) + 0x8000u;
            unsigned u3 = __builtin_bit_cast(unsigned, p[3]) + 0x8000u;
            pk[i][0] = __builtin_amdgcn_perm(u1, u0, 0x07060302u);
            pk[i][1] = __builtin_amdgcn_perm(u3, u2, 0x07060302u);
        }
        lsum += ls;

        // P[q=qm][key=16i+4quad+{0..3}] : 4x ds_write_b64
#pragma unroll
        for (int i = 0; i < 4; i++) {
            uint2 pv; pv.x = pk[i][0]; pv.y = pk[i][1];
            *(uint2*)((unsigned short*)Pw + qm * 72 + 16 * i + 4 * quad) = pv;
        }

        // O += P V : A = P rows (b128), B = V^T rows
        bf16x8 ap0 = *(const bf16x8*)(Pw + qm * 72 + quad * 8);
        bf16x8 ap1 = *(const bf16x8*)(Pw + qm * 72 + 32 + quad * 8);
#pragma unroll
        for (int jd = 0; jd < 4; jd++) {
            oacc[jd] = __builtin_amdgcn_mfma_f32_16x16x32_bf16(
                ap0, bv[jd][0], oacc[jd], 0, 0, 0);
            oacc[jd] = __builtin_amdgcn_mfma_f32_16x16x32_bf16(
                ap1, bv[jd][1], oacc[jd], 0, 0, 0);
        }
        __syncthreads();   // publishes next buffer, protects the overwritten one
    }

    // epilogue: reduce l across quads (lane-local rows), divide, store
    float lf = lsum;
    lf += __shfl_xor(lf, 16);
    lf += __shfl_xor(lf, 32);               // full l for q = bb+qm
#pragma unroll
    for (int r = 0; r < 4; r++) {
        float lr = __shfl(lf, 4 * quad + r);  // l for q = bb+4quad+r
        float inv = 1.0f / lr;
        int qrow = bb + 4 * quad + r;
#pragma unroll
        for (int jd = 0; jd < 4; jd++)
            O[base + (size_t)qrow * D_ + 16 * jd + qm] =
                f2bf(oacc[jd][r] * inv);
    }
}

// ---------------------------------------------------------------------------
extern "C" void kernel_launch(void* const* d_in, const int* in_sizes, int n_in,
                              void* d_out, int out_size, void* d_ws, size_t ws_size,
                              hipStream_t stream) {
    (void)in_sizes; (void)n_in; (void)out_size; (void)ws_size;
    const float* x  = (const float*)d_in[0];
    const float* Wq = (const float*)d_in[1];
    const float* bq = (const float*)d_in[2];
    const float* Wk = (const float*)d_in[3];
    const float* bk = (const float*)d_in[4];
    const float* Wv = (const float*)d_in[5];
    const float* bv = (const float*)d_in[6];
    const float* Wo = (const float*)d_in[7];
    const float* bo = (const float*)d_in[8];
    float* out = (float*)d_out;

    const size_t n = (size_t)B_ * H_ * S_ * D_;  // 6291456
    // ws layout (46 MB):
    //  [0,n):   xb (dead after QKV gemm)
    //  [n,2n):  Qb -> Ob (attn reads only its own Q rows before writing them)
    //  [2n,3n): Kb
    //  [3n,4n): Vtb  (V written transposed by QKV gemm epilogue, z=2)
    //  [4n,+):  Wt, 4 x 768*768 bf16
    __bf16* xb  = (__bf16*)d_ws;
    __bf16* Qb  = xb + n;
    __bf16* Kb  = xb + 2 * n;
    __bf16* Vtb = xb + 3 * n;
    __bf16* Wt  = xb + 4 * n;
    __bf16* Ob  = Qb;

    cvt_x<<<6144, 256, 0, stream>>>(x, xb);
    wtrans<<<dim3(12, 12, 4), 256, 0, stream>>>(Wq, Wk, Wv, Wo, Wt);
    gemm_bf<true><<<dim3(6, 64, 3), 256, 0, stream>>>(
        xb, Wt, bq, bk, bv, nullptr, Qb);
    attn_k<<<dim3(32, 48), 256, 0, stream>>>(Qb, Kb, Vtb, Ob);
    gemm_bf<false><<<dim3(6, 64, 1), 256, 0, stream>>>(
        Ob, Wt + 3 * (size_t)E_ * E_, bo, nullptr, nullptr, out, nullptr);
}

// Round 10
// 264.989 us; speedup vs baseline: 1.0770x; 1.0770x over previous
//
#include <hip/hip_runtime.h>
#include <hip/hip_bf16.h>
#include <cstdint>
#include <cstddef>

#define B_ 4
#define S_ 2048
#define E_ 768
#define H_ 12
#define D_ 64

typedef __bf16 bf16x8 __attribute__((ext_vector_type(8)));
typedef float f32x4 __attribute__((ext_vector_type(4)));

__constant__ float c_slopes[12] = {
    0.6299605249f, 0.396850263f, 0.25f, 0.1574901312f,
    0.0992125657f, 0.0625f, 0.0393725328f, 0.0248031414f,
    0.015625f, 0.0098431332f, 0.0062007854f, 0.00390625f};

__device__ __forceinline__ unsigned short f2bf_u(float f) {
    unsigned u = __builtin_bit_cast(unsigned, f);
    u += 0x7fffu + ((u >> 16) & 1u);   // round-to-nearest-even
    return (unsigned short)(u >> 16);
}
__device__ __forceinline__ __bf16 f2bf(float f) {
    unsigned short s = f2bf_u(f);
    return __builtin_bit_cast(__bf16, s);
}

// async global->LDS, 16B per lane, dest = wave-uniform base + lane*16
__device__ __forceinline__ void gload_lds16(const void* g, void* l) {
    __builtin_amdgcn_global_load_lds(
        (const __attribute__((address_space(1))) unsigned int*)g,
        (__attribute__((address_space(3))) unsigned int*)l, 16, 0, 0);
}

// ---------------------------------------------------------------------------
// prep: x fp32 -> bf16 (6.29M elems)
// ---------------------------------------------------------------------------
__global__ __launch_bounds__(256) void cvt_x(const float* __restrict__ src,
                                             __bf16* __restrict__ dst) {
    int i = (blockIdx.x * 256 + threadIdx.x) * 4;
    float4 v = *(const float4*)(src + i);
    ushort4 o;
    o.x = f2bf_u(v.x); o.y = f2bf_u(v.y); o.z = f2bf_u(v.z); o.w = f2bf_u(v.w);
    *(ushort4*)((unsigned short*)dst + i) = o;
}

// ---------------------------------------------------------------------------
// prep: W fp32 [k][n] -> Wt bf16 [n][k]; z picks which of 4 matrices
// ---------------------------------------------------------------------------
__global__ __launch_bounds__(256) void wtrans(const float* __restrict__ W0,
                                              const float* __restrict__ W1,
                                              const float* __restrict__ W2,
                                              const float* __restrict__ W3,
                                              __bf16* __restrict__ Wt) {
    const float* W = blockIdx.z == 0 ? W0 : blockIdx.z == 1 ? W1
                   : blockIdx.z == 2 ? W2 : W3;
    __bf16* out = Wt + (size_t)blockIdx.z * E_ * E_;
    __shared__ alignas(16) __bf16 ts[64 * 72];
    const int t = threadIdx.x;
    const int k0 = blockIdx.y * 64, n0 = blockIdx.x * 64;
#pragma unroll
    for (int i = 0; i < 4; i++) {
        int idx = i * 256 + t;          // 1024 float4 chunks
        int row = idx >> 4, c4 = idx & 15;
        float4 v = *(const float4*)(W + (size_t)(k0 + row) * E_ + n0 + c4 * 4);
        ts[(c4 * 4 + 0) * 72 + row] = f2bf(v.x);
        ts[(c4 * 4 + 1) * 72 + row] = f2bf(v.y);
        ts[(c4 * 4 + 2) * 72 + row] = f2bf(v.z);
        ts[(c4 * 4 + 3) * 72 + row] = f2bf(v.w);
    }
    __syncthreads();
#pragma unroll
    for (int i = 0; i < 2; i++) {
        int idx = i * 256 + t;          // 512 chunks of 8 bf16
        int r = idx >> 3, c8 = idx & 7;
        *(uint4*)((unsigned short*)out + (size_t)(n0 + r) * E_ + k0 + c8 * 8) =
            *(const uint4*)((const unsigned short*)ts + r * 72 + c8 * 8);
    }
}

// ---------------------------------------------------------------------------
// GEMM: out = A(8192x768 bf16) @ Wt^T + bias. Wt is [n][k] bf16.
// R7 single-BK32 m97-style staging (best measured). Bias prefetched into
// registers before the K-loop (scattered 4B loads were latency-exposed in
// the epilogue). z=2 -> V written transposed [bh][d][s].
// ---------------------------------------------------------------------------
template <bool PERM>
__global__ __launch_bounds__(256) void gemm_bf(
    const __bf16* __restrict__ A, const __bf16* __restrict__ WtAll,
    const float* __restrict__ b0, const float* __restrict__ b1,
    const float* __restrict__ b2,
    float* __restrict__ outF, __bf16* __restrict__ outB_base) {
    constexpr int Kd = E_, N = E_;
    __shared__ alignas(16) __bf16 Asm[128 * 32];   // 64B rows, no pad (m97)
    __shared__ alignas(16) __bf16 Bsm[128 * 32];

    const int t = threadIdx.x;
    const int w = t >> 6, lane = t & 63;
    const int qm = lane & 15, quad = lane >> 4;
    const int m0 = blockIdx.y * 128, n0 = blockIdx.x * 128;
    const int wm = (w >> 1) * 64, wn = (w & 1) * 64;
    const int z = blockIdx.z;
    const __bf16* Wt = WtAll + (size_t)z * Kd * N;
    const float* bias = PERM ? (z == 0 ? b0 : z == 1 ? b1 : b2) : b0;
    __bf16* outB = PERM ? outB_base + (size_t)z * ((size_t)B_ * S_ * E_) : nullptr;

    // bias prefetch: 4 scattered loads issued before the K-loop
    float bvv[4];
#pragma unroll
    for (int j = 0; j < 4; j++) bvv[j] = bias[n0 + wn + j * 16 + qm];

    // staging: 1024B wave-chunk = 16 rows x 64B; wave w owns chunks {2w,2w+1}
    const int crow = lane >> 2;       // row within chunk
    const int ccol = lane & 3;        // 16B quarter within row

    f32x4 acc[4][4] = {};

    for (int k0 = 0; k0 < Kd; k0 += 32) {
#pragma unroll
        for (int cc = 0; cc < 2; cc++) {
            int chunk = w * 2 + cc;
            int row = chunk * 16 + crow;
            gload_lds16((const unsigned short*)A + (size_t)(m0 + row) * Kd + k0 + ccol * 8,
                        Asm + chunk * 512);
            gload_lds16((const unsigned short*)Wt + (size_t)(n0 + row) * Kd + k0 + ccol * 8,
                        Bsm + chunk * 512);
        }
        __syncthreads();

        bf16x8 af[4], bg[4];
#pragma unroll
        for (int i = 0; i < 4; i++)
            af[i] = *(const bf16x8*)(Asm + (wm + i * 16 + qm) * 32 + quad * 8);
#pragma unroll
        for (int j = 0; j < 4; j++)
            bg[j] = *(const bf16x8*)(Bsm + (wn + j * 16 + qm) * 32 + quad * 8);
#pragma unroll
        for (int i = 0; i < 4; i++)
#pragma unroll
            for (int j = 0; j < 4; j++)
                acc[i][j] = __builtin_amdgcn_mfma_f32_16x16x32_bf16(
                    af[i], bg[j], acc[i][j], 0, 0, 0);
        __syncthreads();
    }

    // epilogue: C/D layout col=lane&15, row=quad*4+reg
#pragma unroll
    for (int i = 0; i < 4; i++) {
#pragma unroll
        for (int j = 0; j < 4; j++) {
            int col = n0 + wn + j * 16 + qm;
            int rowb = m0 + wm + i * 16 + quad * 4;
            if (PERM && z == 2) {
                // V -> Vt [bh][d][s]: rows r are consecutive s, pack 4 bf16
                int b = rowb >> 11, s = rowb & (S_ - 1);
                int h = col >> 6, d = col & (D_ - 1);
                unsigned short pk4[4];
#pragma unroll
                for (int r = 0; r < 4; r++) pk4[r] = f2bf_u(acc[i][j][r] + bvv[j]);
                uint2 pv;
                pv.x = (unsigned)pk4[0] | ((unsigned)pk4[1] << 16);
                pv.y = (unsigned)pk4[2] | ((unsigned)pk4[3] << 16);
                *(uint2*)((unsigned short*)outB +
                          ((size_t)(b * H_ + h) * D_ + d) * S_ + s) = pv;
            } else {
#pragma unroll
                for (int r = 0; r < 4; r++) {
                    int row = rowb + r;
                    float val = acc[i][j][r] + bvv[j];
                    if (PERM) {
                        int b = row >> 11, s = row & (S_ - 1);
                        int h = col >> 6, d = col & (D_ - 1);
                        outB[(((size_t)(b * H_ + h)) * S_ + s) * D_ + d] = f2bf(val);
                    } else {
                        outF[(size_t)row * N + col] = val;
                    }
                }
            }
        }
    }
}

// ---------------------------------------------------------------------------
// Flash attention (S^T formulation, analytic-max softmax, causal + ALiBi).
// R10: async global_load_lds staging into SPLIT-HALF K/V arrays (64B rows,
// gload-compatible contiguous wave chunks, m97-verified bank pattern).
// Removes the VGPR round-trip and staging ds_writes; LDS 25.2 KB + VGPR 44
// -> 6 blocks/CU: all 1536 blocks co-resident, zero dispatch tail.
// Single-buffer 2-barrier structure (R9 proved dbuf@3blk < sbuf@5blk).
// ---------------------------------------------------------------------------
__global__ __launch_bounds__(256, 6) void attn_k(
    const __bf16* __restrict__ Q, const __bf16* __restrict__ K,
    const __bf16* __restrict__ Vt, __bf16* __restrict__ O) {
    __shared__ alignas(16) __bf16 Ksm[2][64 * 32];   // [dhalf][key][d%32]
    __shared__ alignas(16) __bf16 Vsm[2][64 * 32];   // [khalf][d][key%32]
    __shared__ alignas(16) __bf16 Psm[4 * 16 * 72];  // per-wave P [q][key]

    const int t = threadIdx.x;
    const int w = t >> 6, lane = t & 63;
    const int qm = lane & 15, quad = lane >> 4;
    const int qt = 31 - (int)blockIdx.x;          // longest first
    const int bh = blockIdx.y;
    const float c2 = c_slopes[bh % H_] * 1.44269504f;     // slope * log2(e)
    const size_t base = (size_t)bh * S_ * D_;

    // Q B-fragments (lane qm = q-col, contiguous over d)
    const int bb = qt * 64 + w * 16;
    const __bf16* qp = Q + base + (size_t)(bb + qm) * D_ + quad * 8;
    bf16x8 qf0 = *(const bf16x8*)qp;
    bf16x8 qf1 = *(const bf16x8*)(qp + 32);

    f32x4 oacc[4] = {};
    float lsum = 0.f;
    __bf16* Pw = Psm + w * 16 * 72;

    // gload staging: wave w stages rows 16w..16w+15 of each array.
    // lane l -> row 16w + (l>>2), 16B quarter (l&3); dest = base + lane*16.
    const int srow = lane >> 2, sq = lane & 3;
    const unsigned short* Kg = (const unsigned short*)K + base +
                               (size_t)(16 * w + srow) * D_ + sq * 8;
    const unsigned short* Vg = (const unsigned short*)Vt + base +
                               (size_t)(16 * w + srow) * S_ + sq * 8;

    for (int kt = 0; kt <= qt; kt++) {
        // async stage: Ksm[h][key][dh] <- K[kt*64+key][32h+dh]
        //              Vsm[h][d][kh]   <- Vt[d][kt*64+32h+kh]
#pragma unroll
        for (int h = 0; h < 2; h++) {
            gload_lds16(Kg + (size_t)(kt * 64) * D_ + 32 * h, Ksm[h] + w * 512);
            gload_lds16(Vg + kt * 64 + 32 * h, Vsm[h] + w * 512);
        }
        __syncthreads();   // (compiler inserts vmcnt(0) drain before barrier)

        // K A-frags (m=key) and V B-frags (n=d) from split halves
        bf16x8 ak[4][2], bv[4][2];
#pragma unroll
        for (int i = 0; i < 4; i++) {
            ak[i][0] = *(const bf16x8*)(Ksm[0] + (16 * i + qm) * 32 + quad * 8);
            ak[i][1] = *(const bf16x8*)(Ksm[1] + (16 * i + qm) * 32 + quad * 8);
        }
#pragma unroll
        for (int jd = 0; jd < 4; jd++) {
            bv[jd][0] = *(const bf16x8*)(Vsm[0] + (16 * jd + qm) * 32 + quad * 8);
            bv[jd][1] = *(const bf16x8*)(Vsm[1] + (16 * jd + qm) * 32 + quad * 8);
        }

        // S^T = K Q^T : lane (qm,quad) reg r holds S^T[key=16i+4quad+r][q=qm]
        f32x4 st[4];
#pragma unroll
        for (int i = 0; i < 4; i++) {
            f32x4 zz = {0.f, 0.f, 0.f, 0.f};
            zz = __builtin_amdgcn_mfma_f32_16x16x32_bf16(ak[i][0], qf0, zz, 0, 0, 0);
            zz = __builtin_amdgcn_mfma_f32_16x16x32_bf16(ak[i][1], qf1, zz, 0, 0, 0);
            st[i] = zz;
        }

        // analytic-max softmax: ALiBi max over keys is at k=0 (slope*(q-k)),
        // so subtracting slope*q gives exponent qk*scale*log2e - c2*key:
        // q-independent, bounded above by ~+4, no shuffles/running max.
        const int qi = bb + qm;
        const bool nomask = (kt * 64 + 63) <= bb;
        float ls = 0.f;
        unsigned pk[4][2];
#pragma unroll
        for (int i = 0; i < 4; i++) {
            float bi = -c2 * (float)(kt * 64 + 16 * i + 4 * quad);
            float p[4];
#pragma unroll
            for (int r = 0; r < 4; r++) {
                float tt = st[i][r] * 0.18033688f + (bi - c2 * (float)r);
                float pp = __builtin_amdgcn_exp2f(tt);
                if (!nomask) {
                    int key = kt * 64 + 16 * i + 4 * quad + r;
                    pp = (key > qi) ? 0.f : pp;
                }
                ls += pp;
                p[r] = pp;
            }
            // pack 4 fp32 -> 4 bf16 (round-half-up + v_perm byte select)
            unsigned u0 = __builtin_bit_cast(unsigned, p[0]) + 0x8000u;
            unsigned u1 = __builtin_bit_cast(unsigned, p[1]) + 0x8000u;
            unsigned u2 = __builtin_bit_cast(unsigned, p[2]) + 0x8000u;
            unsigned u3 = __builtin_bit_cast(unsigned, p[3]) + 0x8000u;
            pk[i][0] = __builtin_amdgcn_perm(u1, u0, 0x07060302u);
            pk[i][1] = __builtin_amdgcn_perm(u3, u2, 0x07060302u);
        }
        lsum += ls;

        // P[q=qm][key=16i+4quad+{0..3}] : 4x ds_write_b64
#pragma unroll
        for (int i = 0; i < 4; i++) {
            uint2 pv; pv.x = pk[i][0]; pv.y = pk[i][1];
            *(uint2*)((unsigned short*)Pw + qm * 72 + 16 * i + 4 * quad) = pv;
        }

        // O += P V : A = P rows (b128), B = V^T rows (keys 0..31 / 32..63)
        bf16x8 ap0 = *(const bf16x8*)(Pw + qm * 72 + quad * 8);
        bf16x8 ap1 = *(const bf16x8*)(Pw + qm * 72 + 32 + quad * 8);
#pragma unroll
        for (int jd = 0; jd < 4; jd++) {
            oacc[jd] = __builtin_amdgcn_mfma_f32_16x16x32_bf16(
                ap0, bv[jd][0], oacc[jd], 0, 0, 0);
            oacc[jd] = __builtin_amdgcn_mfma_f32_16x16x32_bf16(
                ap1, bv[jd][1], oacc[jd], 0, 0, 0);
        }
        __syncthreads();   // protect buffers before next iteration's gloads
    }

    // epilogue: reduce l across quads (lane-local rows), divide, store
    float lf = lsum;
    lf += __shfl_xor(lf, 16);
    lf += __shfl_xor(lf, 32);               // full l for q = bb+qm
#pragma unroll
    for (int r = 0; r < 4; r++) {
        float lr = __shfl(lf, 4 * quad + r);  // l for q = bb+4quad+r
        float inv = 1.0f / lr;
        int qrow = bb + 4 * quad + r;
#pragma unroll
        for (int jd = 0; jd < 4; jd++)
            O[base + (size_t)qrow * D_ + 16 * jd + qm] =
                f2bf(oacc[jd][r] * inv);
    }
}

// ---------------------------------------------------------------------------
extern "C" void kernel_launch(void* const* d_in, const int* in_sizes, int n_in,
                              void* d_out, int out_size, void* d_ws, size_t ws_size,
                              hipStream_t stream) {
    (void)in_sizes; (void)n_in; (void)out_size; (void)ws_size;
    const float* x  = (const float*)d_in[0];
    const float* Wq = (const float*)d_in[1];
    const float* bq = (const float*)d_in[2];
    const float* Wk = (const float*)d_in[3];
    const float* bk = (const float*)d_in[4];
    const float* Wv = (const float*)d_in[5];
    const float* bv = (const float*)d_in[6];
    const float* Wo = (const float*)d_in[7];
    const float* bo = (const float*)d_in[8];
    float* out = (float*)d_out;

    const size_t n = (size_t)B_ * H_ * S_ * D_;  // 6291456
    // ws layout (46 MB):
    //  [0,n):   xb (dead after QKV gemm)
    //  [n,2n):  Qb -> Ob (attn reads only its own Q rows before writing them)
    //  [2n,3n): Kb
    //  [3n,4n): Vtb  (V written transposed by QKV gemm epilogue, z=2)
    //  [4n,+):  Wt, 4 x 768*768 bf16
    __bf16* xb  = (__bf16*)d_ws;
    __bf16* Qb  = xb + n;
    __bf16* Kb  = xb + 2 * n;
    __bf16* Vtb = xb + 3 * n;
    __bf16* Wt  = xb + 4 * n;
    __bf16* Ob  = Qb;

    cvt_x<<<6144, 256, 0, stream>>>(x, xb);
    wtrans<<<dim3(12, 12, 4), 256, 0, stream>>>(Wq, Wk, Wv, Wo, Wt);
    gemm_bf<true><<<dim3(6, 64, 3), 256, 0, stream>>>(
        xb, Wt, bq, bk, bv, nullptr, Qb);
    attn_k<<<dim3(32, 48), 256, 0, stream>>>(Qb, Kb, Vtb, Ob);
    gemm_bf<false><<<dim3(6, 64, 1), 256, 0, stream>>>(
        Ob, Wt + 3 * (size_t)E_ * E_, bo, nullptr, nullptr, out, nullptr);
}